// Round 11
// baseline (3872.922 us; speedup 1.0000x reference)
//
#include <hip/hip_runtime.h>
#include <stdint.h>

// Fused self-attention, bf16-MFMA.
// proj: 320x512-tile GEMM (flux-minimizing: 1.53GB staged vs R9's 2.12GB),
// BK=32, 1024 threads (16 waves 4x4, per-wave 80x128), ring-3 LDS 156KB,
// paired-row XOR swizzle (two 64B logical rows per 128B phys row), counted
// vmcnt. Grid 15x16=240 blocks = 1 round. PV: 256x256 (R4-best form).
// B=8, C=3840, C8=480, N=1024. GEMMs: C[m][n] = sum_k A[m][k]*BT[n][k].

typedef __attribute__((ext_vector_type(4))) float f32x4;
typedef __attribute__((ext_vector_type(8))) short bf16x8;
typedef __attribute__((ext_vector_type(4))) short s16x4;

namespace {
constexpr int kB = 8, kC = 3840, kC8 = 480, kN = 1024;
constexpr int kM  = 4800;       // combined rows: q 480 + k 480 + v 3840
constexpr int kNT = kB * kN;    // 8192 columns (batch folded)
}

__device__ __forceinline__ short f2bf(float f) {
    union { float f; uint32_t u; } v; v.f = f;
    return (short)((v.u + 0x7FFFu + ((v.u >> 16) & 1u)) >> 16);
}

__device__ __forceinline__ void gl16(const void* g, void* l) {
    __builtin_amdgcn_global_load_lds(
        (const __attribute__((address_space(1))) void*)g,
        (__attribute__((address_space(3))) void*)(uint32_t)(uintptr_t)l,
        16, 0, 0);
}

#define DSR(d, a, o) asm volatile("ds_read_b128 %0, %1 offset:" o \
    : "=v"(d) : "v"(a) : "memory")

// ---------------- weight combine + bf16 convert ----------------
__global__ __launch_bounds__(256)
void convert_wc(const float* __restrict__ Wq, const float* __restrict__ Wk,
                const float* __restrict__ Wv, short* __restrict__ Wc)
{
    const size_t g  = (size_t)blockIdx.x * 256 + threadIdx.x;
    const size_t e0 = g * 8;
    if (e0 >= (size_t)kM * kC) return;
    const int r = (int)(e0 / kC);
    const int c = (int)(e0 % kC);
    const float* src;
    if (r < kC8)          src = Wq + (size_t)r * kC + c;
    else if (r < 2 * kC8) src = Wk + (size_t)(r - kC8) * kC + c;
    else                  src = Wv + (size_t)(r - 2 * kC8) * kC + c;
    bf16x8 o;
    float4 a = *(const float4*)src;
    float4 b = *(const float4*)(src + 4);
    o[0]=f2bf(a.x); o[1]=f2bf(a.y); o[2]=f2bf(a.z); o[3]=f2bf(a.w);
    o[4]=f2bf(b.x); o[5]=f2bf(b.y); o[6]=f2bf(b.z); o[7]=f2bf(b.w);
    *(bf16x8*)(Wc + e0) = o;
}

__global__ __launch_bounds__(256)
void convert_bias(const float* __restrict__ bq, const float* __restrict__ bk,
                  const float* __restrict__ bv, float* __restrict__ biasC)
{
    const int r = blockIdx.x * 256 + threadIdx.x;
    if (r >= kM) return;
    biasC[r] = r < kC8 ? bq[r] : r < 2*kC8 ? bk[r - kC8] : bv[r - 2*kC8];
}

// ---------------- x (B,C,N) fp32 -> xbT (B*N, C) bf16 ----------------
__global__ __launch_bounds__(256)
void transpose_x(const float* __restrict__ x, short* __restrict__ xbT)
{
    __shared__ float t[32][33];
    const int tid = threadIdx.x;
    const int b = blockIdx.z, c0 = blockIdx.y * 32, n0 = blockIdx.x * 32;
    const int r = tid >> 3, q4 = (tid & 7) * 4;
    float4 v = *(const float4*)(x + ((size_t)b * kC + c0 + r) * kN + n0 + q4);
    t[r][q4] = v.x; t[r][q4+1] = v.y; t[r][q4+2] = v.z; t[r][q4+3] = v.w;
    __syncthreads();
    s16x4 o;
    o[0] = f2bf(t[q4+0][r]); o[1] = f2bf(t[q4+1][r]);
    o[2] = f2bf(t[q4+2][r]); o[3] = f2bf(t[q4+3][r]);
    *(s16x4*)(xbT + (size_t)(b * kN + n0 + r) * kC + c0 + q4) = o;
}

// ---------------- qkv rows 0..959 -> qT/kT (B*N, 480) bf16 ----------------
__global__ __launch_bounds__(256)
void transpose_qk(const short* __restrict__ qkv, short* __restrict__ qT,
                  short* __restrict__ kT)
{
    __shared__ short t[32][36];
    const int tid = threadIdx.x;
    const int o0 = blockIdx.y * 32, bn0 = blockIdx.x * 32;
    const int r = tid >> 3, q4 = (tid & 7) * 4;
    s16x4 v = *(const s16x4*)(qkv + (size_t)(o0 + r) * kNT + bn0 + q4);
    t[r][q4] = v[0]; t[r][q4+1] = v[1]; t[r][q4+2] = v[2]; t[r][q4+3] = v[3];
    __syncthreads();
    s16x4 o;
    o[0] = t[q4+0][r]; o[1] = t[q4+1][r]; o[2] = t[q4+2][r]; o[3] = t[q4+3][r];
    const int oc = o0 + q4;
    short* dst = (o0 < kC8) ? (qT + (size_t)(bn0 + r) * kC8 + oc)
                            : (kT + (size_t)(bn0 + r) * kC8 + (oc - kC8));
    *(s16x4*)dst = o;
}

// ---------------- legacy 128x128 MFMA GEMM (energy only) ----------------
__global__ __launch_bounds__(256) void gemm_bt_e(
    const short* __restrict__ Abase, int lda,
    const short* __restrict__ Bbase, int ldb,
    int ksteps, long zsa, long zsb, long zso,
    float* __restrict__ eout)
{
    __shared__ __align__(16) short ldsA[128 * 32];
    __shared__ __align__(16) short ldsB[128 * 32];

    const int tid  = threadIdx.x;
    const int lane = tid & 63;
    const int w    = tid >> 6;
    const int m0 = blockIdx.y * 128;
    const int n0 = blockIdx.x * 128;
    const int z  = blockIdx.z;

    const char* Ab = (const char*)(Abase + (size_t)z * zsa);
    const char* Bb = (const char*)(Bbase + (size_t)z * zsb);
    const size_t ldab = (size_t)lda * 2, ldbb = (size_t)ldb * 2;

    const int srow  = w * 16 + (lane >> 2);
    const int scolb = (lane & 3) * 16;
    char* lA = (char*)ldsA;
    char* lB = (char*)ldsB;

    f32x4 acc[4][4];
#pragma unroll
    for (int i = 0; i < 4; ++i)
#pragma unroll
        for (int j = 0; j < 4; ++j) acc[i][j] = (f32x4)0.f;

    const int wm = (w >> 1) * 64, wn = (w & 1) * 64;
    const int fr = lane & 15;
    const int kb = (lane >> 4) * 16;

    for (int s = 0; s < ksteps; ++s) {
        const int k0b = s * 64;
        if (s) __syncthreads();
        gl16(Ab + (size_t)(m0 + srow)      * ldab + k0b + scolb, lA + w * 1024);
        gl16(Ab + (size_t)(m0 + 64 + srow) * ldab + k0b + scolb, lA + 4096 + w * 1024);
        gl16(Bb + (size_t)(n0 + srow)      * ldbb + k0b + scolb, lB + w * 1024);
        gl16(Bb + (size_t)(n0 + 64 + srow) * ldbb + k0b + scolb, lB + 4096 + w * 1024);
        __syncthreads();

        bf16x8 af[4], bfv[4];
#pragma unroll
        for (int f = 0; f < 4; ++f) {
            af[f]  = *(const bf16x8*)(lA + (wm + f * 16 + fr) * 64 + kb);
            bfv[f] = *(const bf16x8*)(lB + (wn + f * 16 + fr) * 64 + kb);
        }
#pragma unroll
        for (int fm = 0; fm < 4; ++fm)
#pragma unroll
            for (int fn = 0; fn < 4; ++fn)
                acc[fm][fn] = __builtin_amdgcn_mfma_f32_16x16x32_bf16(
                    af[fm], bfv[fn], acc[fm][fn], 0, 0, 0);
    }

    const int rbase = (lane >> 4) * 4;
    float* eb = eout + (size_t)z * zso;
#pragma unroll
    for (int fm = 0; fm < 4; ++fm)
#pragma unroll
        for (int fn = 0; fn < 4; ++fn)
#pragma unroll
            for (int r = 0; r < 4; ++r)
                eb[(size_t)(m0 + wm + fm*16 + rbase + r) * kN + (n0 + wn + fn*16 + fr)]
                    = acc[fm][fn][r];
}

// ---------------- proj GEMM: 320x512 tile, BK=32, ring-3 ----------------
// 1024 threads (16 waves 4x4), per-wave 80x128 (fm=5, fn=8), acc 5x8.
// LDS: 3 slots x (A 20KB + B 32KB) = 156KB. Paired-row layout: phys row p
// (128B) holds logical rows 2p,2p+1 (64B each), XOR-swizzled by (p&7)<<4.
// Staging: 52 chunks of 1KB; wave w owns chunks {w, w+16, w+32} (+{48+w}
// for w<4) -> per-wave 3 or 4 gl16/step; counted vmcnt branches on w<4.
__global__ __launch_bounds__(1024) void gemm512(
    const short* __restrict__ Wc, const short* __restrict__ xbT,
    short* __restrict__ qkv, const float* __restrict__ biasC)
{
    __shared__ __align__(16) char lds[159744];   // 3 x 53248

    const int tid  = threadIdx.x;
    const int lane = tid & 63;
    const int w    = tid >> 6;         // 0..15
    const int m0 = blockIdx.x * 320;   // 15 m-tiles (fastest)
    const int n0 = blockIdx.y * 512;   // 16 n-tiles

    const char* Ab = (const char*)Wc;
    const char* Bb = (const char*)xbT;
    const size_t ldab = (size_t)kC * 2, ldbb = (size_t)kC * 2;

    // ---- staging per-lane source mapping (paired-row + XOR, verified) ----
    // dst phys: p = chunk*8 + (lane>>3), c = (lane&7)*16. With p&7 == lane>>3:
    // v = (lane&7) ^ (lane>>3); logical row offset = 2*(lane>>3) + (v>>2);
    // logical col byte = (v&3)<<4.
    const int lp = lane >> 3, ls = lane & 7;
    const int v_ = ls ^ lp;
    const int dR = 2 * lp + (v_ >> 2);          // row within 16-row chunk
    const int gcS = (v_ & 3) << 4;              // source col byte within 64B

    // my chunks: {w, w+16, w+32} + (w<4 ? {48+w} : {})
    const char* s0; const char* s1; const char* s2; const char* s3 = nullptr;
    uint32_t d0, d1, d2, d3 = 0;
#define CHUNK(C_, SP, DO)                                                      \
    do { int c_ = (C_);                                                        \
        if (c_ < 20) { SP = Ab + (size_t)(m0 + c_ * 16 + dR) * ldab + gcS;     \
                       DO = (uint32_t)c_ * 1024u; }                            \
        else { int cb = c_ - 20;                                               \
               SP = Bb + (size_t)(n0 + cb * 16 + dR) * ldbb + gcS;             \
               DO = 20480u + (uint32_t)cb * 1024u; }                           \
    } while (0)
    CHUNK(w,      s0, d0);
    CHUNK(w + 16, s1, d1);
    CHUNK(w + 32, s2, d2);
    if (w < 4) CHUNK(w + 48, s3, d3);
#undef CHUNK

#define STAGE512(S, SLOTBASE)                                                  \
    do {                                                                       \
        const size_t kb_ = (size_t)(S) * 64;                                   \
        gl16(s0 + kb_, (SLOTBASE) + d0);                                       \
        gl16(s1 + kb_, (SLOTBASE) + d1);                                       \
        gl16(s2 + kb_, (SLOTBASE) + d2);                                       \
        if (w < 4) gl16(s3 + kb_, (SLOTBASE) + d3);                            \
    } while (0)

    // ---- fragment-read addresses ----
    // logical row R = base + fr -> p = R>>1 (p&7 == fr>>1 since bases %16==0),
    // c = (((fr&1)<<6) | (kq<<4)) ^ ((fr>>1)<<4); fm/fn advance = 1024B.
    const uint32_t lbase = (uint32_t)(uintptr_t)&lds[0];
    const int wr = w >> 2, wc2 = w & 3;        // wave tile: 80 rows x 128 cols
    const int fr = lane & 15, kq = lane >> 4;
    const uint32_t fcol = ((uint32_t)(((fr & 1) << 6) | (kq << 4)))
                        ^ (((uint32_t)(fr >> 1)) << 4);
    const uint32_t aoff = (uint32_t)((wr * 40 + (fr >> 1)) * 128) + fcol;
    const uint32_t boff = 20480u + (uint32_t)((wc2 * 64 + (fr >> 1)) * 128) + fcol;

    f32x4 acc[5][8];
#pragma unroll
    for (int i = 0; i < 5; ++i)
#pragma unroll
        for (int j = 0; j < 8; ++j) acc[i][j] = (f32x4)0.f;

    // ---- prologue: stage tiles 0,1,2 ----
    STAGE512(0, lds);
    STAGE512(1, lds + 53248);
    STAGE512(2, lds + 106496);

    const int ns = kC / 32;   // 120
    for (int s = 0; s < ns; ++s) {
        // slot-s landed; leave stages s+1,s+2 in flight (3-4 ops each/wave)
        if (s + 2 < ns) {
            if (w < 4) asm volatile("s_waitcnt vmcnt(8)" ::: "memory");
            else       asm volatile("s_waitcnt vmcnt(6)" ::: "memory");
        } else if (s + 1 < ns) {
            if (w < 4) asm volatile("s_waitcnt vmcnt(4)" ::: "memory");
            else       asm volatile("s_waitcnt vmcnt(3)" ::: "memory");
        } else {
            asm volatile("s_waitcnt vmcnt(0)" ::: "memory");
        }
        __builtin_amdgcn_s_barrier();

        const int slot = s - (s / 3) * 3;          // s % 3
        const uint32_t sb = lbase + (uint32_t)slot * 53248u;
        const uint32_t aa = sb + aoff, bb = sb + boff;

        bf16x8 a[5], b[8];
        DSR(b[0], bb, "0");    DSR(b[1], bb, "1024");
        DSR(b[2], bb, "2048"); DSR(b[3], bb, "3072");
        DSR(b[4], bb, "4096"); DSR(b[5], bb, "5120");
        DSR(b[6], bb, "6144"); DSR(b[7], bb, "7168");
        DSR(a[0], aa, "0");    DSR(a[1], aa, "1024");
        DSR(a[2], aa, "2048"); DSR(a[3], aa, "3072");
        DSR(a[4], aa, "4096");

        asm volatile("s_waitcnt lgkmcnt(0)" ::: "memory");
        __builtin_amdgcn_sched_barrier(0);
        __builtin_amdgcn_s_barrier();              // all waves done reading slot
        if (s + 3 < ns)
            STAGE512(s + 3, lds + slot * 53248);   // (s+3)%3 == slot
        __builtin_amdgcn_sched_barrier(0);

        __builtin_amdgcn_s_setprio(1);
#pragma unroll
        for (int fm = 0; fm < 5; ++fm)
#pragma unroll
            for (int fn = 0; fn < 8; ++fn)
                acc[fm][fn] = __builtin_amdgcn_mfma_f32_16x16x32_bf16(
                    a[fm], b[fn], acc[fm][fn], 0, 0, 0);
        __builtin_amdgcn_s_setprio(0);
    }
#undef STAGE512

    // ---- epilogue: D mapping col = lane&15, row = (lane>>4)*4 + reg ----
    const int rbase = kq * 4;
#pragma unroll
    for (int fm = 0; fm < 5; ++fm) {
#pragma unroll
        for (int rr = 0; rr < 4; ++rr) {
            const int gm = m0 + wr * 80 + fm * 16 + rbase + rr;
            const float bias = biasC[gm];
#pragma unroll
            for (int fn = 0; fn < 8; ++fn) {
                const int gn = n0 + wc2 * 128 + fn * 16 + fr;
                qkv[(size_t)gm * kNT + gn] = f2bf(acc[fm][fn][rr] + bias);
            }
        }
    }
}

// ---------------- PV GEMM: 256x256 tile (R4-best form) ----------------
__global__ __launch_bounds__(512) void gemm256pv(
    const short* __restrict__ Abase, int lda,
    const short* __restrict__ Bbase, int ldb,
    int ksteps, long zsa, long zsb, long zso,
    const float* __restrict__ x, const float* __restrict__ gamma,
    float* __restrict__ out)
{
    __shared__ __align__(16) char lds[131072];

    const int tid  = threadIdx.x;
    const int lane = tid & 63;
    const int w    = tid >> 6;

    const int m0 = blockIdx.x * 256;
    const int n0 = blockIdx.y * 256;
    const int bz = blockIdx.z;

    const char* Ab = (const char*)(Abase + (size_t)bz * zsa);
    const char* Bb = (const char*)(Bbase + (size_t)bz * zsb);
    const size_t ldab = (size_t)lda * 2, ldbb = (size_t)ldb * 2;

    const int r8  = tid >> 3;
    const int scb = ((tid & 7) * 16) ^ ((r8 & 7) << 4);

#define STAGE(S, SLOTBASE)                                                     \
    do {                                                                       \
        const size_t kb_ = (size_t)(S) * 128;                                  \
        _Pragma("unroll")                                                      \
        for (int i_ = 0; i_ < 4; ++i_)                                         \
            gl16(Ab + (size_t)(m0 + r8 + 64 * i_) * ldab + kb_ + scb,          \
                 (SLOTBASE) + i_ * 8192 + w * 1024);                           \
        _Pragma("unroll")                                                      \
        for (int i_ = 0; i_ < 4; ++i_)                                         \
            gl16(Bb + (size_t)(n0 + r8 + 64 * i_) * ldbb + kb_ + scb,          \
                 (SLOTBASE) + 32768 + i_ * 8192 + w * 1024);                   \
    } while (0)

    const uint32_t lbase = (uint32_t)(uintptr_t)&lds[0];
    const int wr = w >> 2, wc = w & 3;
    const int fr = lane & 15, kq = lane >> 4;
    const uint32_t xorv = (uint32_t)((fr & 7) << 4);
    const uint32_t aoff0 = (uint32_t)((wr*128 + fr) * 128) + (((uint32_t)(kq*16)) ^ xorv);
    const uint32_t aoff1 = (uint32_t)((wr*128 + fr) * 128) + (((uint32_t)(64 + kq*16)) ^ xorv);
    const uint32_t boff0 = 32768u + (uint32_t)((wc*64 + fr) * 128) + (((uint32_t)(kq*16)) ^ xorv);
    const uint32_t boff1 = 32768u + (uint32_t)((wc*64 + fr) * 128) + (((uint32_t)(64 + kq*16)) ^ xorv);

    f32x4 acc[8][4];
#pragma unroll
    for (int i = 0; i < 8; ++i)
#pragma unroll
        for (int j = 0; j < 4; ++j) acc[i][j] = (f32x4)0.f;

    STAGE(0, lds);
    STAGE(1, lds + 65536);

    const int ns = ksteps;
    for (int s = 0; s < ns; ++s) {
        const uint32_t cur = (uint32_t)(s & 1);
        if (s + 1 < ns) asm volatile("s_waitcnt vmcnt(8)" ::: "memory");
        else            asm volatile("s_waitcnt vmcnt(0)" ::: "memory");
        __builtin_amdgcn_sched_barrier(0);
        __builtin_amdgcn_s_barrier();
        __builtin_amdgcn_sched_barrier(0);

        const uint32_t sb = lbase + cur * 65536u;
        const uint32_t aa0 = sb + aoff0, aa1 = sb + aoff1;
        const uint32_t bb0 = sb + boff0, bb1 = sb + boff1;

        bf16x8 b0v[4], b1v[4], a0[8], a1[8];
        DSR(b0v[0], bb0, "0");    DSR(b0v[1], bb0, "2048");
        DSR(b0v[2], bb0, "4096"); DSR(b0v[3], bb0, "6144");
        DSR(b1v[0], bb1, "0");    DSR(b1v[1], bb1, "2048");
        DSR(b1v[2], bb1, "4096"); DSR(b1v[3], bb1, "6144");
        DSR(a0[0], aa0, "0");    DSR(a0[1], aa0, "2048");
        DSR(a1[0], aa1, "0");    DSR(a1[1], aa1, "2048");
        DSR(a0[2], aa0, "4096"); DSR(a0[3], aa0, "6144");
        DSR(a1[2], aa1, "4096"); DSR(a1[3], aa1, "6144");

        asm volatile("s_waitcnt lgkmcnt(4)" ::: "memory");
        __builtin_amdgcn_sched_barrier(0);
        __builtin_amdgcn_s_setprio(1);
#pragma unroll
        for (int fm = 0; fm < 2; ++fm)
#pragma unroll
            for (int fn = 0; fn < 4; ++fn) {
                acc[fm][fn] = __builtin_amdgcn_mfma_f32_16x16x32_bf16(a0[fm], b0v[fn], acc[fm][fn], 0, 0, 0);
                acc[fm][fn] = __builtin_amdgcn_mfma_f32_16x16x32_bf16(a1[fm], b1v[fn], acc[fm][fn], 0, 0, 0);
            }
        __builtin_amdgcn_s_setprio(0);

        DSR(a0[4], aa0, "8192"); DSR(a0[5], aa0, "10240");
        DSR(a1[4], aa1, "8192"); DSR(a1[5], aa1, "10240");
        asm volatile("s_waitcnt lgkmcnt(4)" ::: "memory");
        __builtin_amdgcn_sched_barrier(0);
        __builtin_amdgcn_s_setprio(1);
#pragma unroll
        for (int fm = 2; fm < 4; ++fm)
#pragma unroll
            for (int fn = 0; fn < 4; ++fn) {
                acc[fm][fn] = __builtin_amdgcn_mfma_f32_16x16x32_bf16(a0[fm], b0v[fn], acc[fm][fn], 0, 0, 0);
                acc[fm][fn] = __builtin_amdgcn_mfma_f32_16x16x32_bf16(a1[fm], b1v[fn], acc[fm][fn], 0, 0, 0);
            }
        __builtin_amdgcn_s_setprio(0);

        DSR(a0[6], aa0, "12288"); DSR(a0[7], aa0, "14336");
        DSR(a1[6], aa1, "12288"); DSR(a1[7], aa1, "14336");
        asm volatile("s_waitcnt lgkmcnt(4)" ::: "memory");
        __builtin_amdgcn_sched_barrier(0);
        __builtin_amdgcn_s_setprio(1);
#pragma unroll
        for (int fm = 4; fm < 6; ++fm)
#pragma unroll
            for (int fn = 0; fn < 4; ++fn) {
                acc[fm][fn] = __builtin_amdgcn_mfma_f32_16x16x32_bf16(a0[fm], b0v[fn], acc[fm][fn], 0, 0, 0);
                acc[fm][fn] = __builtin_amdgcn_mfma_f32_16x16x32_bf16(a1[fm], b1v[fn], acc[fm][fn], 0, 0, 0);
            }
        __builtin_amdgcn_s_setprio(0);

        asm volatile("s_waitcnt lgkmcnt(0)" ::: "memory");
        __builtin_amdgcn_sched_barrier(0);
        __builtin_amdgcn_s_barrier();
        __builtin_amdgcn_sched_barrier(0);

        if (s + 2 < ns)
            STAGE(s + 2, lds + cur * 65536);
        __builtin_amdgcn_sched_barrier(0);

        __builtin_amdgcn_s_setprio(1);
#pragma unroll
        for (int fm = 6; fm < 8; ++fm)
#pragma unroll
            for (int fn = 0; fn < 4; ++fn) {
                acc[fm][fn] = __builtin_amdgcn_mfma_f32_16x16x32_bf16(a0[fm], b0v[fn], acc[fm][fn], 0, 0, 0);
                acc[fm][fn] = __builtin_amdgcn_mfma_f32_16x16x32_bf16(a1[fm], b1v[fn], acc[fm][fn], 0, 0, 0);
            }
        __builtin_amdgcn_s_setprio(0);
    }
#undef STAGE

    const int rbase = kq * 4;
    const float g = gamma[0];
    const float* xb = x + (size_t)bz * zso;
    float* ob = out + (size_t)bz * zso;
#pragma unroll
    for (int fm = 0; fm < 8; ++fm)
#pragma unroll
        for (int fn = 0; fn < 4; ++fn)
#pragma unroll
            for (int rr = 0; rr < 4; ++rr) {
                const size_t idx = (size_t)(m0 + wr*128 + fm*16 + rbase + rr) * kN
                                 + (n0 + wc*64 + fn*16 + fr);
                ob[idx] = g * acc[fm][fn][rr] + xb[idx];
            }
}

// ---------------- row softmax fp32 -> bf16 ----------------
__global__ __launch_bounds__(256)
void softmax_bf(const float* __restrict__ e, short* __restrict__ attnb)
{
    const int i = blockIdx.x, b = blockIdx.y, tid = threadIdx.x;
    const float* row = e + ((size_t)b * kN + i) * kN;

    float4 vv = *(const float4*)(row + tid * 4);
    float m = fmaxf(fmaxf(vv.x, vv.y), fmaxf(vv.z, vv.w));

    __shared__ float red[8];
#pragma unroll
    for (int off = 32; off > 0; off >>= 1)
        m = fmaxf(m, __shfl_down(m, off));
    if ((tid & 63) == 0) red[tid >> 6] = m;
    __syncthreads();
    m = fmaxf(fmaxf(red[0], red[1]), fmaxf(red[2], red[3]));

    float e0 = expf(vv.x - m), e1 = expf(vv.y - m);
    float e2 = expf(vv.z - m), e3 = expf(vv.w - m);
    float s = e0 + e1 + e2 + e3;
#pragma unroll
    for (int off = 32; off > 0; off >>= 1)
        s += __shfl_down(s, off);
    if ((tid & 63) == 0) red[4 + (tid >> 6)] = s;
    __syncthreads();
    s = red[4] + red[5] + red[6] + red[7];

    const float inv = 1.0f / s;
    s16x4 o;
    o[0] = f2bf(e0 * inv); o[1] = f2bf(e1 * inv);
    o[2] = f2bf(e2 * inv); o[3] = f2bf(e3 * inv);
    *(s16x4*)(attnb + ((size_t)b * kN + i) * kN + tid * 4) = o;
}

extern "C" void kernel_launch(void* const* d_in, const int* in_sizes, int n_in,
                              void* d_out, int out_size, void* d_ws, size_t ws_size,
                              hipStream_t stream) {
    const float* x     = (const float*)d_in[0];
    const float* Wq    = (const float*)d_in[1];
    const float* bq    = (const float*)d_in[2];
    const float* Wk    = (const float*)d_in[3];
    const float* bk    = (const float*)d_in[4];
    const float* Wv    = (const float*)d_in[5];
    const float* bv    = (const float*)d_in[6];
    const float* gamma = (const float*)d_in[7];
    float* out = (float*)d_out;

    char* base = (char*)d_ws;
    short* xbT   = (short*)(base);
    short* attnb = (short*)(base);
    short* qT    = (short*)(base + 16777216);
    short* kT    = (short*)(base + 24641536);
    short* Wc    = (short*)(base + 62914560);
    float* attnf = (float*)(base + 62914560);
    float* biasC = (float*)(base + 100270080);
    short* qkv   = (short*)(base + 100289536);

    convert_wc  <<<9000, 256, 0, stream>>>(Wq, Wk, Wv, Wc);
    convert_bias<<<19, 256, 0, stream>>>(bq, bk, bv, biasC);
    transpose_x <<<dim3(32, 120, 8), 256, 0, stream>>>(x, xbT);

    // proj: (4800 x 3840) * (8192 x 3840)^T -> qkv
    // 15 x 16 = 240 blocks x 1024 threads, single dispatch round
    gemm512<<<dim3(15, 16), 1024, 0, stream>>>(Wc, xbT, qkv, biasC);

    transpose_qk<<<dim3(256, 30, 1), 256, 0, stream>>>(qkv, qT, kT);

    // energy: per batch (1024 x 480) * (1024 x 480)^T -> E fp32
    gemm_bt_e<<<dim3(8, 8, 8), 256, 0, stream>>>(
        qT, kC8, kT, kC8, kC8 / 32,
        (long)kN * kC8, (long)kN * kC8, (long)kN * kN, attnf);

    softmax_bf<<<dim3(kN, kB), 256, 0, stream>>>(attnf, attnb);

    // PV: per batch (3840 x 1024) * (1024 x 1024)^T -> out = gamma*acc + x
    gemm256pv<<<dim3(15, 4, 8), 512, 0, stream>>>(
        qkv + (size_t)960 * kNT, kNT, attnb, kN, kN / 64,
        (long)kN, (long)kN * kN, (long)kC * kN,
        x, gamma, out);
}

// Round 12
// 476.372 us; speedup vs baseline: 8.1300x; 8.1300x over previous
//
#include <hip/hip_runtime.h>
#include <stdint.h>

// Fused self-attention, bf16-MFMA.
// proj: 320x256 tile (R9-proven geometry), BK=32, ring-4 LDS (4 x 36KB =
// 144KB) -> 3 stages in flight (counted vmcnt 15/12), paired-row XOR swizzle
// (R11-verified mapping: two 64B logical rows per 128B phys row).
// 512 threads (8 waves 2x4, per-wave 160x64). PV: 256x256 (R4-best form).
// B=8, C=3840, C8=480, N=1024. GEMMs: C[m][n] = sum_k A[m][k]*BT[n][k].

typedef __attribute__((ext_vector_type(4))) float f32x4;
typedef __attribute__((ext_vector_type(8))) short bf16x8;
typedef __attribute__((ext_vector_type(4))) short s16x4;

namespace {
constexpr int kB = 8, kC = 3840, kC8 = 480, kN = 1024;
constexpr int kM  = 4800;       // combined rows: q 480 + k 480 + v 3840
constexpr int kNT = kB * kN;    // 8192 columns (batch folded)
}

__device__ __forceinline__ short f2bf(float f) {
    union { float f; uint32_t u; } v; v.f = f;
    return (short)((v.u + 0x7FFFu + ((v.u >> 16) & 1u)) >> 16);
}

__device__ __forceinline__ void gl16(const void* g, void* l) {
    __builtin_amdgcn_global_load_lds(
        (const __attribute__((address_space(1))) void*)g,
        (__attribute__((address_space(3))) void*)(uint32_t)(uintptr_t)l,
        16, 0, 0);
}

#define DSR(d, a, o) asm volatile("ds_read_b128 %0, %1 offset:" o \
    : "=v"(d) : "v"(a) : "memory")

// ---------------- weight combine + bf16 convert ----------------
__global__ __launch_bounds__(256)
void convert_wc(const float* __restrict__ Wq, const float* __restrict__ Wk,
                const float* __restrict__ Wv, short* __restrict__ Wc)
{
    const size_t g  = (size_t)blockIdx.x * 256 + threadIdx.x;
    const size_t e0 = g * 8;
    if (e0 >= (size_t)kM * kC) return;
    const int r = (int)(e0 / kC);
    const int c = (int)(e0 % kC);
    const float* src;
    if (r < kC8)          src = Wq + (size_t)r * kC + c;
    else if (r < 2 * kC8) src = Wk + (size_t)(r - kC8) * kC + c;
    else                  src = Wv + (size_t)(r - 2 * kC8) * kC + c;
    bf16x8 o;
    float4 a = *(const float4*)src;
    float4 b = *(const float4*)(src + 4);
    o[0]=f2bf(a.x); o[1]=f2bf(a.y); o[2]=f2bf(a.z); o[3]=f2bf(a.w);
    o[4]=f2bf(b.x); o[5]=f2bf(b.y); o[6]=f2bf(b.z); o[7]=f2bf(b.w);
    *(bf16x8*)(Wc + e0) = o;
}

__global__ __launch_bounds__(256)
void convert_bias(const float* __restrict__ bq, const float* __restrict__ bk,
                  const float* __restrict__ bv, float* __restrict__ biasC)
{
    const int r = blockIdx.x * 256 + threadIdx.x;
    if (r >= kM) return;
    biasC[r] = r < kC8 ? bq[r] : r < 2*kC8 ? bk[r - kC8] : bv[r - 2*kC8];
}

// ---------------- x (B,C,N) fp32 -> xbT (B*N, C) bf16 ----------------
__global__ __launch_bounds__(256)
void transpose_x(const float* __restrict__ x, short* __restrict__ xbT)
{
    __shared__ float t[32][33];
    const int tid = threadIdx.x;
    const int b = blockIdx.z, c0 = blockIdx.y * 32, n0 = blockIdx.x * 32;
    const int r = tid >> 3, q4 = (tid & 7) * 4;
    float4 v = *(const float4*)(x + ((size_t)b * kC + c0 + r) * kN + n0 + q4);
    t[r][q4] = v.x; t[r][q4+1] = v.y; t[r][q4+2] = v.z; t[r][q4+3] = v.w;
    __syncthreads();
    s16x4 o;
    o[0] = f2bf(t[q4+0][r]); o[1] = f2bf(t[q4+1][r]);
    o[2] = f2bf(t[q4+2][r]); o[3] = f2bf(t[q4+3][r]);
    *(s16x4*)(xbT + (size_t)(b * kN + n0 + r) * kC + c0 + q4) = o;
}

// ---------------- qkv rows 0..959 -> qT/kT (B*N, 480) bf16 ----------------
__global__ __launch_bounds__(256)
void transpose_qk(const short* __restrict__ qkv, short* __restrict__ qT,
                  short* __restrict__ kT)
{
    __shared__ short t[32][36];
    const int tid = threadIdx.x;
    const int o0 = blockIdx.y * 32, bn0 = blockIdx.x * 32;
    const int r = tid >> 3, q4 = (tid & 7) * 4;
    s16x4 v = *(const s16x4*)(qkv + (size_t)(o0 + r) * kNT + bn0 + q4);
    t[r][q4] = v[0]; t[r][q4+1] = v[1]; t[r][q4+2] = v[2]; t[r][q4+3] = v[3];
    __syncthreads();
    s16x4 o;
    o[0] = t[q4+0][r]; o[1] = t[q4+1][r]; o[2] = t[q4+2][r]; o[3] = t[q4+3][r];
    const int oc = o0 + q4;
    short* dst = (o0 < kC8) ? (qT + (size_t)(bn0 + r) * kC8 + oc)
                            : (kT + (size_t)(bn0 + r) * kC8 + (oc - kC8));
    *(s16x4*)dst = o;
}

// ---------------- legacy 128x128 MFMA GEMM (energy only) ----------------
__global__ __launch_bounds__(256) void gemm_bt_e(
    const short* __restrict__ Abase, int lda,
    const short* __restrict__ Bbase, int ldb,
    int ksteps, long zsa, long zsb, long zso,
    float* __restrict__ eout)
{
    __shared__ __align__(16) short ldsA[128 * 32];
    __shared__ __align__(16) short ldsB[128 * 32];

    const int tid  = threadIdx.x;
    const int lane = tid & 63;
    const int w    = tid >> 6;
    const int m0 = blockIdx.y * 128;
    const int n0 = blockIdx.x * 128;
    const int z  = blockIdx.z;

    const char* Ab = (const char*)(Abase + (size_t)z * zsa);
    const char* Bb = (const char*)(Bbase + (size_t)z * zsb);
    const size_t ldab = (size_t)lda * 2, ldbb = (size_t)ldb * 2;

    const int srow  = w * 16 + (lane >> 2);
    const int scolb = (lane & 3) * 16;
    char* lA = (char*)ldsA;
    char* lB = (char*)ldsB;

    f32x4 acc[4][4];
#pragma unroll
    for (int i = 0; i < 4; ++i)
#pragma unroll
        for (int j = 0; j < 4; ++j) acc[i][j] = (f32x4)0.f;

    const int wm = (w >> 1) * 64, wn = (w & 1) * 64;
    const int fr = lane & 15;
    const int kb = (lane >> 4) * 16;

    for (int s = 0; s < ksteps; ++s) {
        const int k0b = s * 64;
        if (s) __syncthreads();
        gl16(Ab + (size_t)(m0 + srow)      * ldab + k0b + scolb, lA + w * 1024);
        gl16(Ab + (size_t)(m0 + 64 + srow) * ldab + k0b + scolb, lA + 4096 + w * 1024);
        gl16(Bb + (size_t)(n0 + srow)      * ldbb + k0b + scolb, lB + w * 1024);
        gl16(Bb + (size_t)(n0 + 64 + srow) * ldbb + k0b + scolb, lB + 4096 + w * 1024);
        __syncthreads();

        bf16x8 af[4], bfv[4];
#pragma unroll
        for (int f = 0; f < 4; ++f) {
            af[f]  = *(const bf16x8*)(lA + (wm + f * 16 + fr) * 64 + kb);
            bfv[f] = *(const bf16x8*)(lB + (wn + f * 16 + fr) * 64 + kb);
        }
#pragma unroll
        for (int fm = 0; fm < 4; ++fm)
#pragma unroll
            for (int fn = 0; fn < 4; ++fn)
                acc[fm][fn] = __builtin_amdgcn_mfma_f32_16x16x32_bf16(
                    af[fm], bfv[fn], acc[fm][fn], 0, 0, 0);
    }

    const int rbase = (lane >> 4) * 4;
    float* eb = eout + (size_t)z * zso;
#pragma unroll
    for (int fm = 0; fm < 4; ++fm)
#pragma unroll
        for (int fn = 0; fn < 4; ++fn)
#pragma unroll
            for (int r = 0; r < 4; ++r)
                eb[(size_t)(m0 + wm + fm*16 + rbase + r) * kN + (n0 + wn + fn*16 + fr)]
                    = acc[fm][fn][r];
}

// ---------------- proj GEMM: 320x256 tile, BK=32, ring-4 ----------------
// 512 threads (8 waves 2x4), per-wave 160x64 (fm=10). LDS: 4 slots x
// (A 20KB + B 16KB) = 144KB. Paired-row layout: phys row p (128B) holds
// logical rows 2p,2p+1 (64B), XOR by (p&7)<<4. Stage = 36 chunks of 1KB;
// wave w owns {w,w+8,w+16,w+24} (+{32+w} if w<4) -> 4 or 5 gl16/step.
// Counted vmcnt leaves up to 3 stages in flight (15/12 per wave class).
__global__ __launch_bounds__(512) void gemm320(
    const short* __restrict__ Wc, const short* __restrict__ xbT,
    short* __restrict__ qkv, const float* __restrict__ biasC)
{
    __shared__ __align__(16) char lds[147456];   // 4 x 36864

    const int tid  = threadIdx.x;
    const int lane = tid & 63;
    const int w    = tid >> 6;         // 0..7
    const int m0 = blockIdx.x * 320;   // 15 m-tiles
    const int n0 = blockIdx.y * 256;   // 32 n-tiles

    const char* Ab = (const char*)Wc;
    const char* Bb = (const char*)xbT;
    const size_t ldab = (size_t)kC * 2, ldbb = (size_t)kC * 2;

    // ---- staging per-lane source mapping (paired-row + XOR; R11-verified) ----
    // chunk = 8 phys rows (1KB) = 16 logical rows. dst phys row p=chunk*8+lp,
    // col (lane&7)*16. v = (lane&7)^lp; logical row off = 2*lp + (v>>2);
    // source col byte = (v&3)<<4.
    const int lp = lane >> 3, ls = lane & 7;
    const int v_ = ls ^ lp;
    const int dR = 2 * lp + (v_ >> 2);
    const int gcS = (v_ & 3) << 4;

    // chunks: A = 0..19 (320 rows), B = 20..35 (256 rows)
    const char* s0; const char* s1; const char* s2; const char* s3;
    const char* s4 = nullptr;
    uint32_t d0, d1, d2, d3, d4 = 0;
#define CHUNK(C_, SP, DO)                                                      \
    do { int c_ = (C_);                                                        \
        if (c_ < 20) { SP = Ab + (size_t)(m0 + c_ * 16 + dR) * ldab + gcS;     \
                       DO = (uint32_t)c_ * 1024u; }                            \
        else { int cb = c_ - 20;                                               \
               SP = Bb + (size_t)(n0 + cb * 16 + dR) * ldbb + gcS;             \
               DO = 20480u + (uint32_t)cb * 1024u; }                           \
    } while (0)
    CHUNK(w,      s0, d0);
    CHUNK(w + 8,  s1, d1);
    CHUNK(w + 16, s2, d2);
    CHUNK(w + 24, s3, d3);
    if (w < 4) CHUNK(w + 32, s4, d4);
#undef CHUNK

#define STAGEK(S, SLOTBASE)                                                    \
    do {                                                                       \
        const size_t kb_ = (size_t)(S) * 64;                                   \
        gl16(s0 + kb_, (SLOTBASE) + d0);                                       \
        gl16(s1 + kb_, (SLOTBASE) + d1);                                       \
        gl16(s2 + kb_, (SLOTBASE) + d2);                                       \
        gl16(s3 + kb_, (SLOTBASE) + d3);                                       \
        if (w < 4) gl16(s4 + kb_, (SLOTBASE) + d4);                            \
    } while (0)

    // ---- fragment-read addresses (paired-row; R11-verified) ----
    // logical row R: p = R>>1; col = (((R&1)<<6)|(kq<<4)) ^ ((p&7)<<4).
    // 16 logical rows = 8 phys rows = 1024B advance per fragment.
    const uint32_t lbase = (uint32_t)(uintptr_t)&lds[0];
    const int wr = w >> 2, wc = w & 3;          // wave tile: 160 rows x 64 cols
    const int fr = lane & 15, kq = lane >> 4;
    const uint32_t fcol = ((uint32_t)(((fr & 1) << 6) | (kq << 4)))
                        ^ (((uint32_t)(fr >> 1)) << 4);
    const uint32_t aoff = (uint32_t)((wr * 80 + (fr >> 1)) * 128) + fcol;
    const uint32_t boff = 20480u + (uint32_t)((wc * 32 + (fr >> 1)) * 128) + fcol;

    f32x4 acc[10][4];
#pragma unroll
    for (int i = 0; i < 10; ++i)
#pragma unroll
        for (int j = 0; j < 4; ++j) acc[i][j] = (f32x4)0.f;

    // ---- prologue: stage K-steps 0..3 into slots 0..3 ----
    STAGEK(0, lds);
    STAGEK(1, lds + 36864);
    STAGEK(2, lds + 73728);
    STAGEK(3, lds + 110592);

    const int ns = kC / 32;   // 120
    for (int s = 0; s < ns; ++s) {
        // wait for stage s; leave later stages (up to 3) in flight
        const int ahead = (ns - 1 - s) < 3 ? (ns - 1 - s) : 3;
        if (ahead == 3) {
            if (w < 4) asm volatile("s_waitcnt vmcnt(15)" ::: "memory");
            else       asm volatile("s_waitcnt vmcnt(12)" ::: "memory");
        } else if (ahead == 2) {
            if (w < 4) asm volatile("s_waitcnt vmcnt(10)" ::: "memory");
            else       asm volatile("s_waitcnt vmcnt(8)" ::: "memory");
        } else if (ahead == 1) {
            if (w < 4) asm volatile("s_waitcnt vmcnt(5)" ::: "memory");
            else       asm volatile("s_waitcnt vmcnt(4)" ::: "memory");
        } else {
            asm volatile("s_waitcnt vmcnt(0)" ::: "memory");
        }
        __builtin_amdgcn_s_barrier();

        const int slot = s & 3;
        const uint32_t sb = lbase + (uint32_t)slot * 36864u;
        const uint32_t aa = sb + aoff, bb = sb + boff;

        bf16x8 a[10], b[4];
        DSR(b[0], bb, "0");    DSR(b[1], bb, "1024");
        DSR(b[2], bb, "2048"); DSR(b[3], bb, "3072");
        DSR(a[0], aa, "0");    DSR(a[1], aa, "1024");
        DSR(a[2], aa, "2048"); DSR(a[3], aa, "3072");
        asm volatile("s_waitcnt lgkmcnt(2)" ::: "memory");   // b0-3,a0,a1 done
        __builtin_amdgcn_sched_barrier(0);
        __builtin_amdgcn_s_setprio(1);
#pragma unroll
        for (int fm = 0; fm < 2; ++fm)
#pragma unroll
            for (int fn = 0; fn < 4; ++fn)
                acc[fm][fn] = __builtin_amdgcn_mfma_f32_16x16x32_bf16(
                    a[fm], b[fn], acc[fm][fn], 0, 0, 0);
        __builtin_amdgcn_s_setprio(0);

        DSR(a[4], aa, "4096"); DSR(a[5], aa, "5120");
        asm volatile("s_waitcnt lgkmcnt(2)" ::: "memory");   // a2,a3 done
        __builtin_amdgcn_sched_barrier(0);
        __builtin_amdgcn_s_setprio(1);
#pragma unroll
        for (int fm = 2; fm < 4; ++fm)
#pragma unroll
            for (int fn = 0; fn < 4; ++fn)
                acc[fm][fn] = __builtin_amdgcn_mfma_f32_16x16x32_bf16(
                    a[fm], b[fn], acc[fm][fn], 0, 0, 0);
        __builtin_amdgcn_s_setprio(0);

        DSR(a[6], aa, "6144"); DSR(a[7], aa, "7168");
        asm volatile("s_waitcnt lgkmcnt(2)" ::: "memory");   // a4,a5 done
        __builtin_amdgcn_sched_barrier(0);
        __builtin_amdgcn_s_setprio(1);
#pragma unroll
        for (int fm = 4; fm < 6; ++fm)
#pragma unroll
            for (int fn = 0; fn < 4; ++fn)
                acc[fm][fn] = __builtin_amdgcn_mfma_f32_16x16x32_bf16(
                    a[fm], b[fn], acc[fm][fn], 0, 0, 0);
        __builtin_amdgcn_s_setprio(0);

        DSR(a[8], aa, "8192"); DSR(a[9], aa, "9216");
        asm volatile("s_waitcnt lgkmcnt(2)" ::: "memory");   // a6,a7 done
        __builtin_amdgcn_sched_barrier(0);
        __builtin_amdgcn_s_setprio(1);
#pragma unroll
        for (int fm = 6; fm < 8; ++fm)
#pragma unroll
            for (int fn = 0; fn < 4; ++fn)
                acc[fm][fn] = __builtin_amdgcn_mfma_f32_16x16x32_bf16(
                    a[fm], b[fn], acc[fm][fn], 0, 0, 0);
        __builtin_amdgcn_s_setprio(0);

        asm volatile("s_waitcnt lgkmcnt(0)" ::: "memory");   // a8,a9 done
        __builtin_amdgcn_sched_barrier(0);
        __builtin_amdgcn_s_barrier();          // all waves done reading slot
        if (s + 4 < ns)
            STAGEK(s + 4, lds + (size_t)slot * 36864);   // (s+4)&3 == slot
        __builtin_amdgcn_sched_barrier(0);
        __builtin_amdgcn_s_setprio(1);
#pragma unroll
        for (int fm = 8; fm < 10; ++fm)
#pragma unroll
            for (int fn = 0; fn < 4; ++fn)
                acc[fm][fn] = __builtin_amdgcn_mfma_f32_16x16x32_bf16(
                    a[fm], b[fn], acc[fm][fn], 0, 0, 0);
        __builtin_amdgcn_s_setprio(0);
    }
#undef STAGEK

    // ---- epilogue: D mapping col = lane&15, row = (lane>>4)*4 + reg ----
    const int rbase = kq * 4;
#pragma unroll
    for (int fm = 0; fm < 10; ++fm) {
#pragma unroll
        for (int rr = 0; rr < 4; ++rr) {
            const int gm = m0 + wr * 160 + fm * 16 + rbase + rr;
            const float bias = biasC[gm];
#pragma unroll
            for (int fn = 0; fn < 4; ++fn) {
                const int gn = n0 + wc * 64 + fn * 16 + fr;
                qkv[(size_t)gm * kNT + gn] = f2bf(acc[fm][fn][rr] + bias);
            }
        }
    }
}

// ---------------- PV GEMM: 256x256 tile (R4-best form) ----------------
__global__ __launch_bounds__(512) void gemm256pv(
    const short* __restrict__ Abase, int lda,
    const short* __restrict__ Bbase, int ldb,
    int ksteps, long zsa, long zsb, long zso,
    const float* __restrict__ x, const float* __restrict__ gamma,
    float* __restrict__ out)
{
    __shared__ __align__(16) char lds[131072];

    const int tid  = threadIdx.x;
    const int lane = tid & 63;
    const int w    = tid >> 6;

    const int m0 = blockIdx.x * 256;
    const int n0 = blockIdx.y * 256;
    const int bz = blockIdx.z;

    const char* Ab = (const char*)(Abase + (size_t)bz * zsa);
    const char* Bb = (const char*)(Bbase + (size_t)bz * zsb);
    const size_t ldab = (size_t)lda * 2, ldbb = (size_t)ldb * 2;

    const int r8  = tid >> 3;
    const int scb = ((tid & 7) * 16) ^ ((r8 & 7) << 4);

#define STAGE(S, SLOTBASE)                                                     \
    do {                                                                       \
        const size_t kb_ = (size_t)(S) * 128;                                  \
        _Pragma("unroll")                                                      \
        for (int i_ = 0; i_ < 4; ++i_)                                         \
            gl16(Ab + (size_t)(m0 + r8 + 64 * i_) * ldab + kb_ + scb,          \
                 (SLOTBASE) + i_ * 8192 + w * 1024);                           \
        _Pragma("unroll")                                                      \
        for (int i_ = 0; i_ < 4; ++i_)                                         \
            gl16(Bb + (size_t)(n0 + r8 + 64 * i_) * ldbb + kb_ + scb,          \
                 (SLOTBASE) + 32768 + i_ * 8192 + w * 1024);                   \
    } while (0)

    const uint32_t lbase = (uint32_t)(uintptr_t)&lds[0];
    const int wr = w >> 2, wc = w & 3;
    const int fr = lane & 15, kq = lane >> 4;
    const uint32_t xorv = (uint32_t)((fr & 7) << 4);
    const uint32_t aoff0 = (uint32_t)((wr*128 + fr) * 128) + (((uint32_t)(kq*16)) ^ xorv);
    const uint32_t aoff1 = (uint32_t)((wr*128 + fr) * 128) + (((uint32_t)(64 + kq*16)) ^ xorv);
    const uint32_t boff0 = 32768u + (uint32_t)((wc*64 + fr) * 128) + (((uint32_t)(kq*16)) ^ xorv);
    const uint32_t boff1 = 32768u + (uint32_t)((wc*64 + fr) * 128) + (((uint32_t)(64 + kq*16)) ^ xorv);

    f32x4 acc[8][4];
#pragma unroll
    for (int i = 0; i < 8; ++i)
#pragma unroll
        for (int j = 0; j < 4; ++j) acc[i][j] = (f32x4)0.f;

    STAGE(0, lds);
    STAGE(1, lds + 65536);

    const int ns = ksteps;
    for (int s = 0; s < ns; ++s) {
        const uint32_t cur = (uint32_t)(s & 1);
        if (s + 1 < ns) asm volatile("s_waitcnt vmcnt(8)" ::: "memory");
        else            asm volatile("s_waitcnt vmcnt(0)" ::: "memory");
        __builtin_amdgcn_sched_barrier(0);
        __builtin_amdgcn_s_barrier();
        __builtin_amdgcn_sched_barrier(0);

        const uint32_t sb = lbase + cur * 65536u;
        const uint32_t aa0 = sb + aoff0, aa1 = sb + aoff1;
        const uint32_t bb0 = sb + boff0, bb1 = sb + boff1;

        bf16x8 b0v[4], b1v[4], a0[8], a1[8];
        DSR(b0v[0], bb0, "0");    DSR(b0v[1], bb0, "2048");
        DSR(b0v[2], bb0, "4096"); DSR(b0v[3], bb0, "6144");
        DSR(b1v[0], bb1, "0");    DSR(b1v[1], bb1, "2048");
        DSR(b1v[2], bb1, "4096"); DSR(b1v[3], bb1, "6144");
        DSR(a0[0], aa0, "0");    DSR(a0[1], aa0, "2048");
        DSR(a1[0], aa1, "0");    DSR(a1[1], aa1, "2048");
        DSR(a0[2], aa0, "4096"); DSR(a0[3], aa0, "6144");
        DSR(a1[2], aa1, "4096"); DSR(a1[3], aa1, "6144");

        asm volatile("s_waitcnt lgkmcnt(4)" ::: "memory");
        __builtin_amdgcn_sched_barrier(0);
        __builtin_amdgcn_s_setprio(1);
#pragma unroll
        for (int fm = 0; fm < 2; ++fm)
#pragma unroll
            for (int fn = 0; fn < 4; ++fn) {
                acc[fm][fn] = __builtin_amdgcn_mfma_f32_16x16x32_bf16(a0[fm], b0v[fn], acc[fm][fn], 0, 0, 0);
                acc[fm][fn] = __builtin_amdgcn_mfma_f32_16x16x32_bf16(a1[fm], b1v[fn], acc[fm][fn], 0, 0, 0);
            }
        __builtin_amdgcn_s_setprio(0);

        DSR(a0[4], aa0, "8192"); DSR(a0[5], aa0, "10240");
        DSR(a1[4], aa1, "8192"); DSR(a1[5], aa1, "10240");
        asm volatile("s_waitcnt lgkmcnt(4)" ::: "memory");
        __builtin_amdgcn_sched_barrier(0);
        __builtin_amdgcn_s_setprio(1);
#pragma unroll
        for (int fm = 2; fm < 4; ++fm)
#pragma unroll
            for (int fn = 0; fn < 4; ++fn) {
                acc[fm][fn] = __builtin_amdgcn_mfma_f32_16x16x32_bf16(a0[fm], b0v[fn], acc[fm][fn], 0, 0, 0);
                acc[fm][fn] = __builtin_amdgcn_mfma_f32_16x16x32_bf16(a1[fm], b1v[fn], acc[fm][fn], 0, 0, 0);
            }
        __builtin_amdgcn_s_setprio(0);

        DSR(a0[6], aa0, "12288"); DSR(a0[7], aa0, "14336");
        DSR(a1[6], aa1, "12288"); DSR(a1[7], aa1, "14336");
        asm volatile("s_waitcnt lgkmcnt(4)" ::: "memory");
        __builtin_amdgcn_sched_barrier(0);
        __builtin_amdgcn_s_setprio(1);
#pragma unroll
        for (int fm = 4; fm < 6; ++fm)
#pragma unroll
            for (int fn = 0; fn < 4; ++fn) {
                acc[fm][fn] = __builtin_amdgcn_mfma_f32_16x16x32_bf16(a0[fm], b0v[fn], acc[fm][fn], 0, 0, 0);
                acc[fm][fn] = __builtin_amdgcn_mfma_f32_16x16x32_bf16(a1[fm], b1v[fn], acc[fm][fn], 0, 0, 0);
            }
        __builtin_amdgcn_s_setprio(0);

        asm volatile("s_waitcnt lgkmcnt(0)" ::: "memory");
        __builtin_amdgcn_sched_barrier(0);
        __builtin_amdgcn_s_barrier();
        __builtin_amdgcn_sched_barrier(0);

        if (s + 2 < ns)
            STAGE(s + 2, lds + cur * 65536);
        __builtin_amdgcn_sched_barrier(0);

        __builtin_amdgcn_s_setprio(1);
#pragma unroll
        for (int fm = 6; fm < 8; ++fm)
#pragma unroll
            for (int fn = 0; fn < 4; ++fn) {
                acc[fm][fn] = __builtin_amdgcn_mfma_f32_16x16x32_bf16(a0[fm], b0v[fn], acc[fm][fn], 0, 0, 0);
                acc[fm][fn] = __builtin_amdgcn_mfma_f32_16x16x32_bf16(a1[fm], b1v[fn], acc[fm][fn], 0, 0, 0);
            }
        __builtin_amdgcn_s_setprio(0);
    }
#undef STAGE

    const int rbase = kq * 4;
    const float g = gamma[0];
    const float* xb = x + (size_t)bz * zso;
    float* ob = out + (size_t)bz * zso;
#pragma unroll
    for (int fm = 0; fm < 8; ++fm)
#pragma unroll
        for (int fn = 0; fn < 4; ++fn)
#pragma unroll
            for (int rr = 0; rr < 4; ++rr) {
                const size_t idx = (size_t)(m0 + wr*128 + fm*16 + rbase + rr) * kN
                                 + (n0 + wc*64 + fn*16 + fr);
                ob[idx] = g * acc[fm][fn][rr] + xb[idx];
            }
}

// ---------------- row softmax fp32 -> bf16 ----------------
__global__ __launch_bounds__(256)
void softmax_bf(const float* __restrict__ e, short* __restrict__ attnb)
{
    const int i = blockIdx.x, b = blockIdx.y, tid = threadIdx.x;
    const float* row = e + ((size_t)b * kN + i) * kN;

    float4 vv = *(const float4*)(row + tid * 4);
    float m = fmaxf(fmaxf(vv.x, vv.y), fmaxf(vv.z, vv.w));

    __shared__ float red[8];
#pragma unroll
    for (int off = 32; off > 0; off >>= 1)
        m = fmaxf(m, __shfl_down(m, off));
    if ((tid & 63) == 0) red[tid >> 6] = m;
    __syncthreads();
    m = fmaxf(fmaxf(red[0], red[1]), fmaxf(red[2], red[3]));

    float e0 = expf(vv.x - m), e1 = expf(vv.y - m);
    float e2 = expf(vv.z - m), e3 = expf(vv.w - m);
    float s = e0 + e1 + e2 + e3;
#pragma unroll
    for (int off = 32; off > 0; off >>= 1)
        s += __shfl_down(s, off);
    if ((tid & 63) == 0) red[4 + (tid >> 6)] = s;
    __syncthreads();
    s = red[4] + red[5] + red[6] + red[7];

    const float inv = 1.0f / s;
    s16x4 o;
    o[0] = f2bf(e0 * inv); o[1] = f2bf(e1 * inv);
    o[2] = f2bf(e2 * inv); o[3] = f2bf(e3 * inv);
    *(s16x4*)(attnb + ((size_t)b * kN + i) * kN + tid * 4) = o;
}

extern "C" void kernel_launch(void* const* d_in, const int* in_sizes, int n_in,
                              void* d_out, int out_size, void* d_ws, size_t ws_size,
                              hipStream_t stream) {
    const float* x     = (const float*)d_in[0];
    const float* Wq    = (const float*)d_in[1];
    const float* bq    = (const float*)d_in[2];
    const float* Wk    = (const float*)d_in[3];
    const float* bk    = (const float*)d_in[4];
    const float* Wv    = (const float*)d_in[5];
    const float* bv    = (const float*)d_in[6];
    const float* gamma = (const float*)d_in[7];
    float* out = (float*)d_out;

    char* base = (char*)d_ws;
    short* xbT   = (short*)(base);
    short* attnb = (short*)(base);
    short* qT    = (short*)(base + 16777216);
    short* kT    = (short*)(base + 24641536);
    short* Wc    = (short*)(base + 62914560);
    float* attnf = (float*)(base + 62914560);
    float* biasC = (float*)(base + 100270080);
    short* qkv   = (short*)(base + 100289536);

    convert_wc  <<<9000, 256, 0, stream>>>(Wq, Wk, Wv, Wc);
    convert_bias<<<19, 256, 0, stream>>>(bq, bk, bv, biasC);
    transpose_x <<<dim3(32, 120, 8), 256, 0, stream>>>(x, xbT);

    // proj: (4800 x 3840) * (8192 x 3840)^T -> qkv
    // 15 x 32 = 480 blocks, 512 threads, ring-4 BK=32
    gemm320<<<dim3(15, 32), 512, 0, stream>>>(Wc, xbT, qkv, biasC);

    transpose_qk<<<dim3(256, 30, 1), 256, 0, stream>>>(qkv, qT, kT);

    // energy: per batch (1024 x 480) * (1024 x 480)^T -> E fp32
    gemm_bt_e<<<dim3(8, 8, 8), 256, 0, stream>>>(
        qT, kC8, kT, kC8, kC8 / 32,
        (long)kN * kC8, (long)kN * kC8, (long)kN * kN, attnf);

    softmax_bf<<<dim3(kN, kB), 256, 0, stream>>>(attnf, attnb);

    // PV: per batch (3840 x 1024) * (1024 x 1024)^T -> out = gamma*acc + x
    gemm256pv<<<dim3(15, 4, 8), 512, 0, stream>>>(
        qkv + (size_t)960 * kNT, kNT, attnb, kN, kN / 64,
        (long)kN, (long)kN * kN, (long)kC * kN,
        x, gamma, out);
}

// Round 13
// 453.725 us; speedup vs baseline: 8.5358x; 1.0499x over previous
//
#include <hip/hip_runtime.h>
#include <stdint.h>

// Fused self-attention, bf16-MFMA. (R9 empirical-optimum configuration.)
// proj: 320x256-tile GEMM (M=4800=15x320 -> 480 blocks = 2 clean rounds),
// BK=64, ring-2 LDS 144KB, counted vmcnt(9)/lgkm(4), XOR swizzle with full
// k-half XOR addressing. PV: 256x256 (R4-best form).
// B=8, C=3840, C8=480, N=1024. GEMMs: C[m][n] = sum_k A[m][k]*BT[n][k].

typedef __attribute__((ext_vector_type(4))) float f32x4;
typedef __attribute__((ext_vector_type(8))) short bf16x8;
typedef __attribute__((ext_vector_type(4))) short s16x4;

namespace {
constexpr int kB = 8, kC = 3840, kC8 = 480, kN = 1024;
constexpr int kM  = 4800;       // combined rows: q 480 + k 480 + v 3840
constexpr int kNT = kB * kN;    // 8192 columns (batch folded)
}

__device__ __forceinline__ short f2bf(float f) {
    union { float f; uint32_t u; } v; v.f = f;
    return (short)((v.u + 0x7FFFu + ((v.u >> 16) & 1u)) >> 16);
}

__device__ __forceinline__ void gl16(const void* g, void* l) {
    __builtin_amdgcn_global_load_lds(
        (const __attribute__((address_space(1))) void*)g,
        (__attribute__((address_space(3))) void*)(uint32_t)(uintptr_t)l,
        16, 0, 0);
}

#define DSR(d, a, o) asm volatile("ds_read_b128 %0, %1 offset:" o \
    : "=v"(d) : "v"(a) : "memory")

// ---------------- weight combine + bf16 convert ----------------
__global__ __launch_bounds__(256)
void convert_wc(const float* __restrict__ Wq, const float* __restrict__ Wk,
                const float* __restrict__ Wv, short* __restrict__ Wc)
{
    const size_t g  = (size_t)blockIdx.x * 256 + threadIdx.x;
    const size_t e0 = g * 8;
    if (e0 >= (size_t)kM * kC) return;
    const int r = (int)(e0 / kC);
    const int c = (int)(e0 % kC);
    const float* src;
    if (r < kC8)          src = Wq + (size_t)r * kC + c;
    else if (r < 2 * kC8) src = Wk + (size_t)(r - kC8) * kC + c;
    else                  src = Wv + (size_t)(r - 2 * kC8) * kC + c;
    bf16x8 o;
    float4 a = *(const float4*)src;
    float4 b = *(const float4*)(src + 4);
    o[0]=f2bf(a.x); o[1]=f2bf(a.y); o[2]=f2bf(a.z); o[3]=f2bf(a.w);
    o[4]=f2bf(b.x); o[5]=f2bf(b.y); o[6]=f2bf(b.z); o[7]=f2bf(b.w);
    *(bf16x8*)(Wc + e0) = o;
}

__global__ __launch_bounds__(256)
void convert_bias(const float* __restrict__ bq, const float* __restrict__ bk,
                  const float* __restrict__ bv, float* __restrict__ biasC)
{
    const int r = blockIdx.x * 256 + threadIdx.x;
    if (r >= kM) return;
    biasC[r] = r < kC8 ? bq[r] : r < 2*kC8 ? bk[r - kC8] : bv[r - 2*kC8];
}

// ---------------- x (B,C,N) fp32 -> xbT (B*N, C) bf16 ----------------
__global__ __launch_bounds__(256)
void transpose_x(const float* __restrict__ x, short* __restrict__ xbT)
{
    __shared__ float t[32][33];
    const int tid = threadIdx.x;
    const int b = blockIdx.z, c0 = blockIdx.y * 32, n0 = blockIdx.x * 32;
    const int r = tid >> 3, q4 = (tid & 7) * 4;
    float4 v = *(const float4*)(x + ((size_t)b * kC + c0 + r) * kN + n0 + q4);
    t[r][q4] = v.x; t[r][q4+1] = v.y; t[r][q4+2] = v.z; t[r][q4+3] = v.w;
    __syncthreads();
    s16x4 o;
    o[0] = f2bf(t[q4+0][r]); o[1] = f2bf(t[q4+1][r]);
    o[2] = f2bf(t[q4+2][r]); o[3] = f2bf(t[q4+3][r]);
    *(s16x4*)(xbT + (size_t)(b * kN + n0 + r) * kC + c0 + q4) = o;
}

// ---------------- qkv rows 0..959 -> qT/kT (B*N, 480) bf16 ----------------
__global__ __launch_bounds__(256)
void transpose_qk(const short* __restrict__ qkv, short* __restrict__ qT,
                  short* __restrict__ kT)
{
    __shared__ short t[32][36];
    const int tid = threadIdx.x;
    const int o0 = blockIdx.y * 32, bn0 = blockIdx.x * 32;
    const int r = tid >> 3, q4 = (tid & 7) * 4;
    s16x4 v = *(const s16x4*)(qkv + (size_t)(o0 + r) * kNT + bn0 + q4);
    t[r][q4] = v[0]; t[r][q4+1] = v[1]; t[r][q4+2] = v[2]; t[r][q4+3] = v[3];
    __syncthreads();
    s16x4 o;
    o[0] = t[q4+0][r]; o[1] = t[q4+1][r]; o[2] = t[q4+2][r]; o[3] = t[q4+3][r];
    const int oc = o0 + q4;
    short* dst = (o0 < kC8) ? (qT + (size_t)(bn0 + r) * kC8 + oc)
                            : (kT + (size_t)(bn0 + r) * kC8 + (oc - kC8));
    *(s16x4*)dst = o;
}

// ---------------- legacy 128x128 MFMA GEMM (energy only) ----------------
__global__ __launch_bounds__(256) void gemm_bt_e(
    const short* __restrict__ Abase, int lda,
    const short* __restrict__ Bbase, int ldb,
    int ksteps, long zsa, long zsb, long zso,
    float* __restrict__ eout)
{
    __shared__ __align__(16) short ldsA[128 * 32];
    __shared__ __align__(16) short ldsB[128 * 32];

    const int tid  = threadIdx.x;
    const int lane = tid & 63;
    const int w    = tid >> 6;
    const int m0 = blockIdx.y * 128;
    const int n0 = blockIdx.x * 128;
    const int z  = blockIdx.z;

    const char* Ab = (const char*)(Abase + (size_t)z * zsa);
    const char* Bb = (const char*)(Bbase + (size_t)z * zsb);
    const size_t ldab = (size_t)lda * 2, ldbb = (size_t)ldb * 2;

    const int srow  = w * 16 + (lane >> 2);
    const int scolb = (lane & 3) * 16;
    char* lA = (char*)ldsA;
    char* lB = (char*)ldsB;

    f32x4 acc[4][4];
#pragma unroll
    for (int i = 0; i < 4; ++i)
#pragma unroll
        for (int j = 0; j < 4; ++j) acc[i][j] = (f32x4)0.f;

    const int wm = (w >> 1) * 64, wn = (w & 1) * 64;
    const int fr = lane & 15;
    const int kb = (lane >> 4) * 16;

    for (int s = 0; s < ksteps; ++s) {
        const int k0b = s * 64;
        if (s) __syncthreads();
        gl16(Ab + (size_t)(m0 + srow)      * ldab + k0b + scolb, lA + w * 1024);
        gl16(Ab + (size_t)(m0 + 64 + srow) * ldab + k0b + scolb, lA + 4096 + w * 1024);
        gl16(Bb + (size_t)(n0 + srow)      * ldbb + k0b + scolb, lB + w * 1024);
        gl16(Bb + (size_t)(n0 + 64 + srow) * ldbb + k0b + scolb, lB + 4096 + w * 1024);
        __syncthreads();

        bf16x8 af[4], bfv[4];
#pragma unroll
        for (int f = 0; f < 4; ++f) {
            af[f]  = *(const bf16x8*)(lA + (wm + f * 16 + fr) * 64 + kb);
            bfv[f] = *(const bf16x8*)(lB + (wn + f * 16 + fr) * 64 + kb);
        }
#pragma unroll
        for (int fm = 0; fm < 4; ++fm)
#pragma unroll
            for (int fn = 0; fn < 4; ++fn)
                acc[fm][fn] = __builtin_amdgcn_mfma_f32_16x16x32_bf16(
                    af[fm], bfv[fn], acc[fm][fn], 0, 0, 0);
    }

    const int rbase = (lane >> 4) * 4;
    float* eb = eout + (size_t)z * zso;
#pragma unroll
    for (int fm = 0; fm < 4; ++fm)
#pragma unroll
        for (int fn = 0; fn < 4; ++fn)
#pragma unroll
            for (int r = 0; r < 4; ++r)
                eb[(size_t)(m0 + wm + fm*16 + rbase + r) * kN + (n0 + wn + fn*16 + fr)]
                    = acc[fm][fn][r];
}

// ---------------- proj GEMM: 320x256 tile, BK=64 ----------------
// 512 threads (8 waves 2x4), per-wave 160x64 (fm=10). Ring-2 LDS
// (2 x [A 40KB | B 32KB] = 144KB). Counted vmcnt(9)/lgkm(4).
__global__ __launch_bounds__(512) void gemm320(
    const short* __restrict__ Wc, const short* __restrict__ xbT,
    short* __restrict__ qkv, const float* __restrict__ biasC)
{
    __shared__ __align__(16) char lds[147456];

    const int tid  = threadIdx.x;
    const int lane = tid & 63;
    const int w    = tid >> 6;
    const int m0 = blockIdx.x * 320;   // 15 m-tiles (fastest)
    const int n0 = blockIdx.y * 256;   // 32 n-tiles

    const char* Ab = (const char*)Wc;
    const char* Bb = (const char*)xbT;
    const size_t ldab = (size_t)kC * 2, ldbb = (size_t)kC * 2;

    const int r8  = tid >> 3;                                   // 0..63
    const int scb = ((tid & 7) * 16) ^ ((r8 & 7) << 4);         // swizzled col byte

#define STAGE320(S, SLOTBASE)                                                  \
    do {                                                                       \
        const size_t kb_ = (size_t)(S) * 128;                                  \
        _Pragma("unroll")                                                      \
        for (int p_ = 0; p_ < 5; ++p_)                                         \
            gl16(Ab + (size_t)(m0 + p_ * 64 + r8) * ldab + kb_ + scb,          \
                 (SLOTBASE) + p_ * 8192 + w * 1024);                           \
        _Pragma("unroll")                                                      \
        for (int p_ = 0; p_ < 4; ++p_)                                         \
            gl16(Bb + (size_t)(n0 + p_ * 64 + r8) * ldbb + kb_ + scb,          \
                 (SLOTBASE) + 40960 + p_ * 8192 + w * 1024);                   \
    } while (0)

    const uint32_t lbase = (uint32_t)(uintptr_t)&lds[0];
    const int wr = w >> 2, wc = w & 3;          // wave tile: 160 rows x 64 cols
    const int fr = lane & 15, kq = lane >> 4;
    const uint32_t xorv = (uint32_t)((fr & 7) << 4);
    // k-half addresses: physical col = logical ^ xorv (full XOR — the +64
    // shortcut is wrong when xorv carries bit 6).
    const uint32_t kcol0 = ((uint32_t)(kq * 16)) ^ xorv;
    const uint32_t kcol1 = ((uint32_t)(64 + kq * 16)) ^ xorv;
    const uint32_t aoff0 = (uint32_t)((wr * 160 + fr) * 128) + kcol0;
    const uint32_t aoff1 = (uint32_t)((wr * 160 + fr) * 128) + kcol1;
    const uint32_t boff0 = 40960u + (uint32_t)((wc * 64 + fr) * 128) + kcol0;
    const uint32_t boff1 = 40960u + (uint32_t)((wc * 64 + fr) * 128) + kcol1;

    f32x4 acc[10][4];
#pragma unroll
    for (int i = 0; i < 10; ++i)
#pragma unroll
        for (int j = 0; j < 4; ++j) acc[i][j] = (f32x4)0.f;

    // prologue: stage tiles 0,1 (18 gl16/thread in flight)
    STAGE320(0, lds);
    STAGE320(1, lds + 73728);

    const int ns = kC / 64;   // 60
    for (int s = 0; s < ns; ++s) {
        if (s + 1 < ns) asm volatile("s_waitcnt vmcnt(9)" ::: "memory");
        else            asm volatile("s_waitcnt vmcnt(0)" ::: "memory");
        __builtin_amdgcn_s_barrier();

        const uint32_t sb = lbase + (uint32_t)(s & 1) * 73728u;
        const uint32_t aa0 = sb + aoff0, aa1 = sb + aoff1;
        const uint32_t bb0 = sb + boff0, bb1 = sb + boff1;

        bf16x8 b0v[4], b1v[4], a0[10], a1[10];
        // B all (8 reads)
        DSR(b0v[0], bb0, "0");    DSR(b0v[1], bb0, "2048");
        DSR(b0v[2], bb0, "4096"); DSR(b0v[3], bb0, "6144");
        DSR(b1v[0], bb1, "0");    DSR(b1v[1], bb1, "2048");
        DSR(b1v[2], bb1, "4096"); DSR(b1v[3], bb1, "6144");
        // A group 0 (fm 0,1)
        DSR(a0[0], aa0, "0");     DSR(a1[0], aa1, "0");
        DSR(a0[1], aa0, "2048");  DSR(a1[1], aa1, "2048");

        // group 1 issue (fm 2,3)
        DSR(a0[2], aa0, "4096");  DSR(a1[2], aa1, "4096");
        DSR(a0[3], aa0, "6144");  DSR(a1[3], aa1, "6144");
        asm volatile("s_waitcnt lgkmcnt(4)" ::: "memory");   // B + g0 done
        __builtin_amdgcn_sched_barrier(0);
        __builtin_amdgcn_s_setprio(1);
#pragma unroll
        for (int fm = 0; fm < 2; ++fm)
#pragma unroll
            for (int fn = 0; fn < 4; ++fn) {
                acc[fm][fn] = __builtin_amdgcn_mfma_f32_16x16x32_bf16(a0[fm], b0v[fn], acc[fm][fn], 0, 0, 0);
                acc[fm][fn] = __builtin_amdgcn_mfma_f32_16x16x32_bf16(a1[fm], b1v[fn], acc[fm][fn], 0, 0, 0);
            }
        __builtin_amdgcn_s_setprio(0);

        DSR(a0[4], aa0, "8192");  DSR(a1[4], aa1, "8192");
        DSR(a0[5], aa0, "10240"); DSR(a1[5], aa1, "10240");
        asm volatile("s_waitcnt lgkmcnt(4)" ::: "memory");   // g1 done
        __builtin_amdgcn_sched_barrier(0);
        __builtin_amdgcn_s_setprio(1);
#pragma unroll
        for (int fm = 2; fm < 4; ++fm)
#pragma unroll
            for (int fn = 0; fn < 4; ++fn) {
                acc[fm][fn] = __builtin_amdgcn_mfma_f32_16x16x32_bf16(a0[fm], b0v[fn], acc[fm][fn], 0, 0, 0);
                acc[fm][fn] = __builtin_amdgcn_mfma_f32_16x16x32_bf16(a1[fm], b1v[fn], acc[fm][fn], 0, 0, 0);
            }
        __builtin_amdgcn_s_setprio(0);

        DSR(a0[6], aa0, "12288"); DSR(a1[6], aa1, "12288");
        DSR(a0[7], aa0, "14336"); DSR(a1[7], aa1, "14336");
        asm volatile("s_waitcnt lgkmcnt(4)" ::: "memory");   // g2 done
        __builtin_amdgcn_sched_barrier(0);
        __builtin_amdgcn_s_setprio(1);
#pragma unroll
        for (int fm = 4; fm < 6; ++fm)
#pragma unroll
            for (int fn = 0; fn < 4; ++fn) {
                acc[fm][fn] = __builtin_amdgcn_mfma_f32_16x16x32_bf16(a0[fm], b0v[fn], acc[fm][fn], 0, 0, 0);
                acc[fm][fn] = __builtin_amdgcn_mfma_f32_16x16x32_bf16(a1[fm], b1v[fn], acc[fm][fn], 0, 0, 0);
            }
        __builtin_amdgcn_s_setprio(0);

        DSR(a0[8], aa0, "16384"); DSR(a1[8], aa1, "16384");
        DSR(a0[9], aa0, "18432"); DSR(a1[9], aa1, "18432");
        asm volatile("s_waitcnt lgkmcnt(4)" ::: "memory");   // g3 done
        __builtin_amdgcn_sched_barrier(0);
        __builtin_amdgcn_s_setprio(1);
#pragma unroll
        for (int fm = 6; fm < 8; ++fm)
#pragma unroll
            for (int fn = 0; fn < 4; ++fn) {
                acc[fm][fn] = __builtin_amdgcn_mfma_f32_16x16x32_bf16(a0[fm], b0v[fn], acc[fm][fn], 0, 0, 0);
                acc[fm][fn] = __builtin_amdgcn_mfma_f32_16x16x32_bf16(a1[fm], b1v[fn], acc[fm][fn], 0, 0, 0);
            }
        __builtin_amdgcn_s_setprio(0);

        asm volatile("s_waitcnt lgkmcnt(0)" ::: "memory");   // g4 done
        __builtin_amdgcn_sched_barrier(0);
        __builtin_amdgcn_s_barrier();          // all waves done reading slot
        if (s + 2 < ns)
            STAGE320(s + 2, lds + (size_t)(s & 1) * 73728);
        __builtin_amdgcn_sched_barrier(0);
        __builtin_amdgcn_s_setprio(1);
#pragma unroll
        for (int fm = 8; fm < 10; ++fm)
#pragma unroll
            for (int fn = 0; fn < 4; ++fn) {
                acc[fm][fn] = __builtin_amdgcn_mfma_f32_16x16x32_bf16(a0[fm], b0v[fn], acc[fm][fn], 0, 0, 0);
                acc[fm][fn] = __builtin_amdgcn_mfma_f32_16x16x32_bf16(a1[fm], b1v[fn], acc[fm][fn], 0, 0, 0);
            }
        __builtin_amdgcn_s_setprio(0);
    }
#undef STAGE320

    // epilogue: D mapping col = lane&15, row = (lane>>4)*4 + reg
    const int rbase = kq * 4;
#pragma unroll
    for (int fm = 0; fm < 10; ++fm) {
#pragma unroll
        for (int rr = 0; rr < 4; ++rr) {
            const int gm = m0 + wr * 160 + fm * 16 + rbase + rr;
            const float bias = biasC[gm];
#pragma unroll
            for (int fn = 0; fn < 4; ++fn) {
                const int gn = n0 + wc * 64 + fn * 16 + fr;
                qkv[(size_t)gm * kNT + gn] = f2bf(acc[fm][fn][rr] + bias);
            }
        }
    }
}

// ---------------- PV GEMM: 256x256 tile (R4-best form) ----------------
__global__ __launch_bounds__(512) void gemm256pv(
    const short* __restrict__ Abase, int lda,
    const short* __restrict__ Bbase, int ldb,
    int ksteps, long zsa, long zsb, long zso,
    const float* __restrict__ x, const float* __restrict__ gamma,
    float* __restrict__ out)
{
    __shared__ __align__(16) char lds[131072];

    const int tid  = threadIdx.x;
    const int lane = tid & 63;
    const int w    = tid >> 6;

    const int m0 = blockIdx.x * 256;
    const int n0 = blockIdx.y * 256;
    const int bz = blockIdx.z;

    const char* Ab = (const char*)(Abase + (size_t)bz * zsa);
    const char* Bb = (const char*)(Bbase + (size_t)bz * zsb);
    const size_t ldab = (size_t)lda * 2, ldbb = (size_t)ldb * 2;

    const int r8  = tid >> 3;
    const int scb = ((tid & 7) * 16) ^ ((r8 & 7) << 4);

#define STAGE(S, SLOTBASE)                                                     \
    do {                                                                       \
        const size_t kb_ = (size_t)(S) * 128;                                  \
        _Pragma("unroll")                                                      \
        for (int i_ = 0; i_ < 4; ++i_)                                         \
            gl16(Ab + (size_t)(m0 + r8 + 64 * i_) * ldab + kb_ + scb,          \
                 (SLOTBASE) + i_ * 8192 + w * 1024);                           \
        _Pragma("unroll")                                                      \
        for (int i_ = 0; i_ < 4; ++i_)                                         \
            gl16(Bb + (size_t)(n0 + r8 + 64 * i_) * ldbb + kb_ + scb,          \
                 (SLOTBASE) + 32768 + i_ * 8192 + w * 1024);                   \
    } while (0)

    const uint32_t lbase = (uint32_t)(uintptr_t)&lds[0];
    const int wr = w >> 2, wc = w & 3;
    const int fr = lane & 15, kq = lane >> 4;
    const uint32_t xorv = (uint32_t)((fr & 7) << 4);
    const uint32_t aoff0 = (uint32_t)((wr*128 + fr) * 128) + (((uint32_t)(kq*16)) ^ xorv);
    const uint32_t aoff1 = (uint32_t)((wr*128 + fr) * 128) + (((uint32_t)(64 + kq*16)) ^ xorv);
    const uint32_t boff0 = 32768u + (uint32_t)((wc*64 + fr) * 128) + (((uint32_t)(kq*16)) ^ xorv);
    const uint32_t boff1 = 32768u + (uint32_t)((wc*64 + fr) * 128) + (((uint32_t)(64 + kq*16)) ^ xorv);

    f32x4 acc[8][4];
#pragma unroll
    for (int i = 0; i < 8; ++i)
#pragma unroll
        for (int j = 0; j < 4; ++j) acc[i][j] = (f32x4)0.f;

    STAGE(0, lds);
    STAGE(1, lds + 65536);

    const int ns = ksteps;
    for (int s = 0; s < ns; ++s) {
        const uint32_t cur = (uint32_t)(s & 1);
        if (s + 1 < ns) asm volatile("s_waitcnt vmcnt(8)" ::: "memory");
        else            asm volatile("s_waitcnt vmcnt(0)" ::: "memory");
        __builtin_amdgcn_sched_barrier(0);
        __builtin_amdgcn_s_barrier();
        __builtin_amdgcn_sched_barrier(0);

        const uint32_t sb = lbase + cur * 65536u;
        const uint32_t aa0 = sb + aoff0, aa1 = sb + aoff1;
        const uint32_t bb0 = sb + boff0, bb1 = sb + boff1;

        bf16x8 b0v[4], b1v[4], a0[8], a1[8];
        DSR(b0v[0], bb0, "0");    DSR(b0v[1], bb0, "2048");
        DSR(b0v[2], bb0, "4096"); DSR(b0v[3], bb0, "6144");
        DSR(b1v[0], bb1, "0");    DSR(b1v[1], bb1, "2048");
        DSR(b1v[2], bb1, "4096"); DSR(b1v[3], bb1, "6144");
        DSR(a0[0], aa0, "0");    DSR(a0[1], aa0, "2048");
        DSR(a1[0], aa1, "0");    DSR(a1[1], aa1, "2048");
        DSR(a0[2], aa0, "4096"); DSR(a0[3], aa0, "6144");
        DSR(a1[2], aa1, "4096"); DSR(a1[3], aa1, "6144");

        asm volatile("s_waitcnt lgkmcnt(4)" ::: "memory");
        __builtin_amdgcn_sched_barrier(0);
        __builtin_amdgcn_s_setprio(1);
#pragma unroll
        for (int fm = 0; fm < 2; ++fm)
#pragma unroll
            for (int fn = 0; fn < 4; ++fn) {
                acc[fm][fn] = __builtin_amdgcn_mfma_f32_16x16x32_bf16(a0[fm], b0v[fn], acc[fm][fn], 0, 0, 0);
                acc[fm][fn] = __builtin_amdgcn_mfma_f32_16x16x32_bf16(a1[fm], b1v[fn], acc[fm][fn], 0, 0, 0);
            }
        __builtin_amdgcn_s_setprio(0);

        DSR(a0[4], aa0, "8192"); DSR(a0[5], aa0, "10240");
        DSR(a1[4], aa1, "8192"); DSR(a1[5], aa1, "10240");
        asm volatile("s_waitcnt lgkmcnt(4)" ::: "memory");
        __builtin_amdgcn_sched_barrier(0);
        __builtin_amdgcn_s_setprio(1);
#pragma unroll
        for (int fm = 2; fm < 4; ++fm)
#pragma unroll
            for (int fn = 0; fn < 4; ++fn) {
                acc[fm][fn] = __builtin_amdgcn_mfma_f32_16x16x32_bf16(a0[fm], b0v[fn], acc[fm][fn], 0, 0, 0);
                acc[fm][fn] = __builtin_amdgcn_mfma_f32_16x16x32_bf16(a1[fm], b1v[fn], acc[fm][fn], 0, 0, 0);
            }
        __builtin_amdgcn_s_setprio(0);

        DSR(a0[6], aa0, "12288"); DSR(a0[7], aa0, "14336");
        DSR(a1[6], aa1, "12288"); DSR(a1[7], aa1, "14336");
        asm volatile("s_waitcnt lgkmcnt(4)" ::: "memory");
        __builtin_amdgcn_sched_barrier(0);
        __builtin_amdgcn_s_setprio(1);
#pragma unroll
        for (int fm = 4; fm < 6; ++fm)
#pragma unroll
            for (int fn = 0; fn < 4; ++fn) {
                acc[fm][fn] = __builtin_amdgcn_mfma_f32_16x16x32_bf16(a0[fm], b0v[fn], acc[fm][fn], 0, 0, 0);
                acc[fm][fn] = __builtin_amdgcn_mfma_f32_16x16x32_bf16(a1[fm], b1v[fn], acc[fm][fn], 0, 0, 0);
            }
        __builtin_amdgcn_s_setprio(0);

        asm volatile("s_waitcnt lgkmcnt(0)" ::: "memory");
        __builtin_amdgcn_sched_barrier(0);
        __builtin_amdgcn_s_barrier();
        __builtin_amdgcn_sched_barrier(0);

        if (s + 2 < ns)
            STAGE(s + 2, lds + cur * 65536);
        __builtin_amdgcn_sched_barrier(0);

        __builtin_amdgcn_s_setprio(1);
#pragma unroll
        for (int fm = 6; fm < 8; ++fm)
#pragma unroll
            for (int fn = 0; fn < 4; ++fn) {
                acc[fm][fn] = __builtin_amdgcn_mfma_f32_16x16x32_bf16(a0[fm], b0v[fn], acc[fm][fn], 0, 0, 0);
                acc[fm][fn] = __builtin_amdgcn_mfma_f32_16x16x32_bf16(a1[fm], b1v[fn], acc[fm][fn], 0, 0, 0);
            }
        __builtin_amdgcn_s_setprio(0);
    }
#undef STAGE

    const int rbase = kq * 4;
    const float g = gamma[0];
    const float* xb = x + (size_t)bz * zso;
    float* ob = out + (size_t)bz * zso;
#pragma unroll
    for (int fm = 0; fm < 8; ++fm)
#pragma unroll
        for (int fn = 0; fn < 4; ++fn)
#pragma unroll
            for (int rr = 0; rr < 4; ++rr) {
                const size_t idx = (size_t)(m0 + wr*128 + fm*16 + rbase + rr) * kN
                                 + (n0 + wc*64 + fn*16 + fr);
                ob[idx] = g * acc[fm][fn][rr] + xb[idx];
            }
}

// ---------------- row softmax fp32 -> bf16 ----------------
__global__ __launch_bounds__(256)
void softmax_bf(const float* __restrict__ e, short* __restrict__ attnb)
{
    const int i = blockIdx.x, b = blockIdx.y, tid = threadIdx.x;
    const float* row = e + ((size_t)b * kN + i) * kN;

    float4 vv = *(const float4*)(row + tid * 4);
    float m = fmaxf(fmaxf(vv.x, vv.y), fmaxf(vv.z, vv.w));

    __shared__ float red[8];
#pragma unroll
    for (int off = 32; off > 0; off >>= 1)
        m = fmaxf(m, __shfl_down(m, off));
    if ((tid & 63) == 0) red[tid >> 6] = m;
    __syncthreads();
    m = fmaxf(fmaxf(red[0], red[1]), fmaxf(red[2], red[3]));

    float e0 = expf(vv.x - m), e1 = expf(vv.y - m);
    float e2 = expf(vv.z - m), e3 = expf(vv.w - m);
    float s = e0 + e1 + e2 + e3;
#pragma unroll
    for (int off = 32; off > 0; off >>= 1)
        s += __shfl_down(s, off);
    if ((tid & 63) == 0) red[4 + (tid >> 6)] = s;
    __syncthreads();
    s = red[4] + red[5] + red[6] + red[7];

    const float inv = 1.0f / s;
    s16x4 o;
    o[0] = f2bf(e0 * inv); o[1] = f2bf(e1 * inv);
    o[2] = f2bf(e2 * inv); o[3] = f2bf(e3 * inv);
    *(s16x4*)(attnb + ((size_t)b * kN + i) * kN + tid * 4) = o;
}

extern "C" void kernel_launch(void* const* d_in, const int* in_sizes, int n_in,
                              void* d_out, int out_size, void* d_ws, size_t ws_size,
                              hipStream_t stream) {
    const float* x     = (const float*)d_in[0];
    const float* Wq    = (const float*)d_in[1];
    const float* bq    = (const float*)d_in[2];
    const float* Wk    = (const float*)d_in[3];
    const float* bk    = (const float*)d_in[4];
    const float* Wv    = (const float*)d_in[5];
    const float* bv    = (const float*)d_in[6];
    const float* gamma = (const float*)d_in[7];
    float* out = (float*)d_out;

    char* base = (char*)d_ws;
    short* xbT   = (short*)(base);
    short* attnb = (short*)(base);
    short* qT    = (short*)(base + 16777216);
    short* kT    = (short*)(base + 24641536);
    short* Wc    = (short*)(base + 62914560);
    float* attnf = (float*)(base + 62914560);
    float* biasC = (float*)(base + 100270080);
    short* qkv   = (short*)(base + 100289536);

    convert_wc  <<<9000, 256, 0, stream>>>(Wq, Wk, Wv, Wc);
    convert_bias<<<19, 256, 0, stream>>>(bq, bk, bv, biasC);
    transpose_x <<<dim3(32, 120, 8), 256, 0, stream>>>(x, xbT);

    // proj: (4800 x 3840) * (8192 x 3840)^T -> qkv
    // 15 x 32 = 480 blocks = 1.875/CU -> exactly 2 dispatch rounds
    gemm320<<<dim3(15, 32), 512, 0, stream>>>(Wc, xbT, qkv, biasC);

    transpose_qk<<<dim3(256, 30, 1), 256, 0, stream>>>(qkv, qT, kT);

    // energy: per batch (1024 x 480) * (1024 x 480)^T -> E fp32
    gemm_bt_e<<<dim3(8, 8, 8), 256, 0, stream>>>(
        qT, kC8, kT, kC8, kC8 / 32,
        (long)kN * kC8, (long)kN * kC8, (long)kN * kN, attnf);

    softmax_bf<<<dim3(kN, kB), 256, 0, stream>>>(attnf, attnb);

    // PV: per batch (3840 x 1024) * (1024 x 1024)^T -> out = gamma*acc + x
    gemm256pv<<<dim3(15, 4, 8), 512, 0, stream>>>(
        qkv + (size_t)960 * kNT, kNT, attnb, kN, kN / 64,
        (long)kN, (long)kN * kN, (long)kC * kN,
        x, gamma, out);
}